// Round 9
// baseline (131.157 us; speedup 1.0000x reference)
//
#include <hip/hip_runtime.h>
#include <hip/hip_bf16.h>
#include <cstdint>
#include <cstddef>

#define VOCAB 32000
#define HIDDEN 2048
#define NLAYERS 6
#define BATCH 512

// GEMM: M=512, N=2048, K=2048 per layer. 32x32x16 MFMA, 64x64 wave tile,
// 128x128 block tile (4 waves 2x2), BK=64, SPLITK=8 -> grid (16,4,8) = 512
// blocks = 2/CU (barrier stagger). LDS reads cut 4x vs 16x16x32 w/ 32x32 tile
// (32 flops/LDS-byte): the round-4..8 structure was LDS-port-bound.
#define BM 128
#define BN 128
#define BK 64
#define SPLITK 8
#define KC (HIDDEN / SPLITK)  // 256 K per block
#define NT (KC / BK)          // 4 K-tiles

typedef __attribute__((ext_vector_type(8))) short bf16x8;
typedef __attribute__((ext_vector_type(16))) float f32x16;

__device__ __forceinline__ unsigned short f2bf(float f) {
  unsigned u = __builtin_bit_cast(unsigned, f);
  u += 0x7fffu + ((u >> 16) & 1u);  // RNE
  return (unsigned short)(u >> 16);
}

__device__ __forceinline__ float bf2f(unsigned short h) {
  return __builtin_bit_cast(float, (unsigned)h << 16);
}

__device__ __forceinline__ float tanh_fast(float x) {
  x = fminf(15.f, fmaxf(-15.f, x));
  float e = __expf(2.f * x);
  return (e - 1.f) / (e + 1.f);
}

__device__ __forceinline__ void gload_lds16(const void* g, void* l) {
  __builtin_amdgcn_global_load_lds(
      (const __attribute__((address_space(1))) void*)g,
      (__attribute__((address_space(3))) void*)l, 16, 0, 0);
}

// ---- prep: z<NLAYERS: hh[l] fp32 [K][N] -> Bt bf16 [N][K]; z==NLAYERS: cvt state ----
__global__ __launch_bounds__(256) void k_prep(const float* __restrict__ hh,
                                              unsigned short* __restrict__ bt,
                                              const float* __restrict__ state,
                                              unsigned short* __restrict__ stb) {
  const int l = blockIdx.z;
  const int t = threadIdx.x;
  if (l == NLAYERS) {
    const int bid = blockIdx.y * 32 + blockIdx.x;
    const int i = (bid * 256 + t) * 4;
    float4 v = *(const float4*)(state + i);
    union { unsigned short h[4]; uint2 u; } o;
    o.h[0] = f2bf(v.x); o.h[1] = f2bf(v.y); o.h[2] = f2bf(v.z); o.h[3] = f2bf(v.w);
    *(uint2*)(stb + i) = o.u;
    return;
  }
  __shared__ unsigned short tile[64][72];  // padded to dodge bank conflicts
  const int n0 = blockIdx.x * 64;
  const int k0 = blockIdx.y * 64;
  const float* src = hh + ((size_t)l * HIDDEN + k0) * HIDDEN + n0;
  const int cr = t >> 4;        // 0..15
  const int cc = (t & 15) * 4;  // 0..60
#pragma unroll
  for (int p = 0; p < 4; ++p) {
    const int r = p * 16 + cr;
    float4 v = *(const float4*)(src + (size_t)r * HIDDEN + cc);
    tile[r][cc + 0] = f2bf(v.x);
    tile[r][cc + 1] = f2bf(v.y);
    tile[r][cc + 2] = f2bf(v.z);
    tile[r][cc + 3] = f2bf(v.w);
  }
  __syncthreads();
  const int nl = t >> 2;        // output row (n), 0..63
  const int kk = (t & 3) * 16;  // k chunk
  unsigned short tmp[16] __attribute__((aligned(16)));
#pragma unroll
  for (int j = 0; j < 16; ++j) tmp[j] = tile[kk + j][nl];
  unsigned short* dst = bt + ((size_t)l * HIDDEN + n0 + nl) * HIDDEN + k0 + kk;
  *(uint4*)(dst) = *(const uint4*)(tmp);
  *(uint4*)(dst + 8) = *(const uint4*)(tmp + 8);
}

// ---- per-layer GEMM: part[kz] = A[512][2048](bf16) @ Bt^T, partials in bf16 ----
__global__ __launch_bounds__(256, 2) void k_gemm(const unsigned short* __restrict__ A,
                                                 const unsigned short* __restrict__ Bt,
                                                 unsigned short* __restrict__ part) {
  __shared__ __attribute__((aligned(16))) unsigned short As[2][BM][BK];  // 32 KB
  __shared__ __attribute__((aligned(16))) unsigned short Bs[2][BN][BK];  // 32 KB

  const int n0 = blockIdx.x * BN;
  const int m0 = blockIdx.y * BM;
  const int kz = blockIdx.z;
  const int kbase = kz * KC;
  const int t = threadIdx.x;
  const int lane = t & 63;
  const int wid = t >> 6;
  const int wm = (wid >> 1) * 64;  // 0 / 64
  const int wn = (wid & 1) * 64;   // 0 / 64

  f32x16 acc00 = {0}, acc01 = {0}, acc10 = {0}, acc11 = {0};

  // T2 both-sides swizzle: pre-swizzled global source + linear LDS dest +
  // swizzled ds_read. Thread t stages chunks {t, t+256, t+512, t+768} of each
  // 128x64 tile (rows r0+{0,32,64,96}; all share r&7 -> same swizzled column).
  const int r0 = t >> 3;                    // 0..31
  const int sc = ((t & 7) ^ (r0 & 7)) * 8;  // swizzled k-chunk (elements)
  const unsigned short* gA = A + (size_t)(m0 + r0) * HIDDEN + kbase + sc;
  const unsigned short* gB = Bt + (size_t)(n0 + r0) * HIDDEN + kbase + sc;
  char* lA = (char*)&As[0][0][0] + wid * 1024;  // + lane*16 implicit
  char* lB = (char*)&Bs[0][0][0] + wid * 1024;

#define STAGE(buf, kt)                                            \
  do {                                                            \
    const int ko = (kt)*BK;                                       \
    gload_lds16(gA + ko, lA + (buf)*16384);                       \
    gload_lds16(gA + 32 * HIDDEN + ko, lA + (buf)*16384 + 4096);  \
    gload_lds16(gA + 64 * HIDDEN + ko, lA + (buf)*16384 + 8192);  \
    gload_lds16(gA + 96 * HIDDEN + ko, lA + (buf)*16384 + 12288); \
    gload_lds16(gB + ko, lB + (buf)*16384);                       \
    gload_lds16(gB + 32 * HIDDEN + ko, lB + (buf)*16384 + 4096);  \
    gload_lds16(gB + 64 * HIDDEN + ko, lB + (buf)*16384 + 8192);  \
    gload_lds16(gB + 96 * HIDDEN + ko, lB + (buf)*16384 + 12288); \
  } while (0)

  // 32x32x16 operand mapping: lane holds row (lane&31), k = (lane>>5)*8 + j.
  const int rowA0 = wm + (lane & 31);   // + fm*32
  const int rowB0 = wn + (lane & 31);   // + fn*32
  const int hk = lane >> 5;             // 0..1
  // (row+32)&7 == row&7, so one swizzle index serves both fragments.
  const int swz = rowA0 & 7;            // == rowB0&7 iff wm==wn mod 8 (both mult of 64) -> yes, = lane&7

#define COMPUTE(buf)                                                                   \
  do {                                                                                 \
    _Pragma("unroll") for (int ks = 0; ks < 4; ++ks) {                                 \
      const int cnk = ((ks * 2 + hk) ^ swz) * 8;                                       \
      bf16x8 a0 = *(const bf16x8*)&As[buf][rowA0][cnk];                                \
      bf16x8 a1 = *(const bf16x8*)&As[buf][rowA0 + 32][cnk];                           \
      bf16x8 b0 = *(const bf16x8*)&Bs[buf][rowB0][cnk];                                \
      bf16x8 b1 = *(const bf16x8*)&Bs[buf][rowB0 + 32][cnk];                           \
      acc00 = __builtin_amdgcn_mfma_f32_32x32x16_bf16(a0, b0, acc00, 0, 0, 0);         \
      acc01 = __builtin_amdgcn_mfma_f32_32x32x16_bf16(a0, b1, acc01, 0, 0, 0);         \
      acc10 = __builtin_amdgcn_mfma_f32_32x32x16_bf16(a1, b0, acc10, 0, 0, 0);         \
      acc11 = __builtin_amdgcn_mfma_f32_32x32x16_bf16(a1, b1, acc11, 0, 0, 0);         \
    }                                                                                  \
  } while (0)

  STAGE(0, 0);
  __syncthreads();
  for (int kt = 0; kt < NT; ++kt) {
    const int buf = kt & 1;
    if (kt + 1 < NT) STAGE(buf ^ 1, kt + 1);
    COMPUTE(buf);
    __syncthreads();
  }

  // C/D layout (m74/m101): col = lane&31, row = (reg&3) + 8*(reg>>2) + 4*(lane>>5).
  unsigned short* p = part + (size_t)kz * ((size_t)BATCH * HIDDEN);
  const int colb = n0 + wn + (lane & 31);
  const int rowb = m0 + wm + 4 * hk;
#define STORE_ACC(accv, fm, fn)                                                   \
  do {                                                                            \
    _Pragma("unroll") for (int r = 0; r < 16; ++r) {                              \
      const int rl = (r & 3) + 8 * (r >> 2);                                      \
      p[(size_t)(rowb + (fm)*32 + rl) * HIDDEN + colb + (fn)*32] = f2bf(accv[r]); \
    }                                                                             \
  } while (0)
  STORE_ACC(acc00, 0, 0);
  STORE_ACC(acc01, 0, 1);
  STORE_ACC(acc10, 1, 0);
  STORE_ACC(acc11, 1, 1);
}

// ---- per-layer epilogue: sum bf16 split-K partials, gate, tanh ----
__global__ __launch_bounds__(256) void k_reduce(const unsigned short* __restrict__ part,
                                                const float* __restrict__ prev,
                                                const float* __restrict__ ihl,
                                                const int* __restrict__ token,
                                                float* __restrict__ outf,
                                                unsigned short* __restrict__ outb) {
  const int idx = (blockIdx.x * 256 + threadIdx.x) * 4;
  const int m = idx >> 11;
  const int n = idx & 2047;
  const size_t MN = (size_t)BATCH * HIDDEN;
  float s[4] = {0.f, 0.f, 0.f, 0.f};
#pragma unroll
  for (int kz = 0; kz < SPLITK; ++kz) {
    union { uint2 u; unsigned short h[4]; } v;
    v.u = *(const uint2*)(part + kz * MN + idx);
#pragma unroll
    for (int j = 0; j < 4; ++j) s[j] += bf2f(v.h[j]);
  }
  float4 pv = *(const float4*)(prev + idx);
  const int tok = token[m];
  float4 g = *(const float4*)(ihl + (size_t)tok * HIDDEN + n);
  float4 r;
  r.x = tanh_fast(pv.x + s[0] * g.x);
  r.y = tanh_fast(pv.y + s[1] * g.y);
  r.z = tanh_fast(pv.z + s[2] * g.z);
  r.w = tanh_fast(pv.w + s[3] * g.w);
  *(float4*)(outf + idx) = r;
  if (outb) {
    union { unsigned short h[4]; uint2 u; } o;
    o.h[0] = f2bf(r.x); o.h[1] = f2bf(r.y); o.h[2] = f2bf(r.z); o.h[3] = f2bf(r.w);
    *(uint2*)(outb + idx) = o.u;
  }
}

extern "C" void kernel_launch(void* const* d_in, const int* in_sizes, int n_in,
                              void* d_out, int out_size, void* d_ws, size_t ws_size,
                              hipStream_t stream) {
  const float* state = (const float*)d_in[0];
  const int* token = (const int*)d_in[1];
  const float* ih = (const float*)d_in[2];
  const float* hh = (const float*)d_in[3];
  float* out = (float*)d_out;

  // ws layout (16B-aligned):
  //   Bt   : 6*2048*2048 bf16 = 50331648 B
  //   stb  : 512*2048 bf16    =  2097152 B
  //   sf   : 512*2048 f32     =  4194304 B
  //   part : 8*512*2048 bf16  = 16777216 B
  char* ws = (char*)d_ws;
  unsigned short* bt = (unsigned short*)ws;
  size_t off = (size_t)NLAYERS * HIDDEN * HIDDEN * 2;
  unsigned short* stb = (unsigned short*)(ws + off);
  off += (size_t)BATCH * HIDDEN * 2;
  float* sf = (float*)(ws + off);
  off += (size_t)BATCH * HIDDEN * 4;
  unsigned short* part = (unsigned short*)(ws + off);

  k_prep<<<dim3(HIDDEN / 64, HIDDEN / 64, NLAYERS + 1), 256, 0, stream>>>(hh, bt, state, stb);

  for (int l = 0; l < NLAYERS; ++l) {
    const bool last = (l == NLAYERS - 1);
    k_gemm<<<dim3(HIDDEN / BN, BATCH / BM, SPLITK), 256, 0, stream>>>(
        stb, bt + (size_t)l * HIDDEN * HIDDEN, part);
    k_reduce<<<dim3((BATCH * HIDDEN) / 1024), 256, 0, stream>>>(
        part, l == 0 ? state : sf, ih + (size_t)l * VOCAB * HIDDEN, token,
        last ? out : sf, last ? nullptr : stb);
  }
}

// Round 10
// 113.104 us; speedup vs baseline: 1.1596x; 1.1596x over previous
//
#include <hip/hip_runtime.h>
#include <hip/hip_bf16.h>
#include <cstdint>
#include <cstddef>

#define VOCAB 32000
#define HIDDEN 2048
#define NLAYERS 6
#define BATCH 512

// GEMM tiling (round-4/8 proven structure): M=512, N=2048, K=2048 per layer
#define BM 64
#define BN 64
#define BK 64
#define SPLITK 4
#define KC (HIDDEN / SPLITK)  // 512 K per block
#define NT (KC / BK)          // 8 K-tiles
#define GEMM_BLOCKS (SPLITK * (HIDDEN / BN) * (BATCH / BM))  // 1024
#define TRANS_BLOCKS ((HIDDEN / 64) * (HIDDEN / 64))         // 1024
#define CVT_BLOCKS ((BATCH * HIDDEN) / 1024)                 // 1024

typedef __attribute__((ext_vector_type(8))) short bf16x8;
typedef __attribute__((ext_vector_type(4))) float f32x4;

__device__ __forceinline__ unsigned short f2bf(float f) {
  unsigned u = __builtin_bit_cast(unsigned, f);
  u += 0x7fffu + ((u >> 16) & 1u);  // RNE
  return (unsigned short)(u >> 16);
}

__device__ __forceinline__ float bf2f(unsigned short h) {
  return __builtin_bit_cast(float, (unsigned)h << 16);
}

__device__ __forceinline__ float tanh_fast(float x) {
  x = fminf(15.f, fmaxf(-15.f, x));
  float e = __expf(2.f * x);
  return (e - 1.f) / (e + 1.f);
}

__device__ __forceinline__ void gload_lds16(const void* g, void* l) {
  __builtin_amdgcn_global_load_lds(
      (const __attribute__((address_space(1))) void*)g,
      (__attribute__((address_space(3))) void*)l, 16, 0, 0);
}

// ---- shared transpose tile body: hh fp32 [K][N] 64x64 tile -> bt bf16 [N][K] ----
__device__ __forceinline__ void transpose_tile(const float* __restrict__ src_layer,
                                               unsigned short* __restrict__ dst_layer,
                                               int n0, int k0, int t,
                                               unsigned short (*tile)[72]) {
  const float* src = src_layer + (size_t)k0 * HIDDEN + n0;
  const int cr = t >> 4;        // 0..15
  const int cc = (t & 15) * 4;  // 0..60
#pragma unroll
  for (int p = 0; p < 4; ++p) {
    const int r = p * 16 + cr;
    float4 v = *(const float4*)(src + (size_t)r * HIDDEN + cc);
    tile[r][cc + 0] = f2bf(v.x);
    tile[r][cc + 1] = f2bf(v.y);
    tile[r][cc + 2] = f2bf(v.z);
    tile[r][cc + 3] = f2bf(v.w);
  }
  __syncthreads();
  const int nl = t >> 2;        // output row (n), 0..63
  const int kk = (t & 3) * 16;  // k chunk
  unsigned short tmp[16] __attribute__((aligned(16)));
#pragma unroll
  for (int j = 0; j < 16; ++j) tmp[j] = tile[kk + j][nl];
  unsigned short* dst = dst_layer + (size_t)(n0 + nl) * HIDDEN + k0 + kk;
  *(uint4*)(dst) = *(const uint4*)(tmp);
  *(uint4*)(dst + 8) = *(const uint4*)(tmp + 8);
}

// ---- prep0: transpose layer 0 + cvt initial state ----
__global__ __launch_bounds__(256) void k_prep0(const float* __restrict__ hh0,
                                               unsigned short* __restrict__ bt0,
                                               const float* __restrict__ state,
                                               unsigned short* __restrict__ stb) {
  __shared__ unsigned short tile[64][72];
  const int wg = blockIdx.x;
  const int t = threadIdx.x;
  if (wg < TRANS_BLOCKS) {
    transpose_tile(hh0, bt0, (wg & 31) * 64, (wg >> 5) * 64, t, tile);
    return;
  }
  const int i = ((wg - TRANS_BLOCKS) * 256 + t) * 4;
  float4 v = *(const float4*)(state + i);
  union { unsigned short h[4]; uint2 u; } o;
  o.h[0] = f2bf(v.x); o.h[1] = f2bf(v.y); o.h[2] = f2bf(v.z); o.h[3] = f2bf(v.w);
  *(uint2*)(stb + i) = o.u;
}

// ---- combined: blocks 0..1023 = layer-l GEMM; 1024..2047 = transpose layer l+1 ----
// GEMM: part[kz] = A @ Bt^T, bf16 partials; 4 waves (2x2), wave tile 32x32,
// XCD-local n-panel remap (neutral r8 mapping kept).
__global__ __launch_bounds__(256, 4) void k_gemm_trans(
    const unsigned short* __restrict__ A, const unsigned short* __restrict__ Bt,
    unsigned short* __restrict__ part,
    const float* __restrict__ hhNext, unsigned short* __restrict__ btNext) {
  __shared__ __attribute__((aligned(16))) unsigned char smem[32768];
  const int t = threadIdx.x;
  const int wg = blockIdx.x;

  if (wg >= GEMM_BLOCKS) {
    // transpose branch (absent for the last layer: grid is 1024 there)
    const int tn = wg - GEMM_BLOCKS;
    transpose_tile(hhNext, btNext, (tn & 31) * 64, (tn >> 5) * 64, t,
                   (unsigned short(*)[72])smem);
    return;
  }

  unsigned short (*As)[BM][BK] = (unsigned short(*)[BM][BK])smem;            // [2]
  unsigned short (*Bs)[BN][BK] = (unsigned short(*)[BN][BK])(smem + 16384);  // [2]

  const int xcd = wg & 7;
  const int idx = wg >> 3;
  const int n0 = (xcd * 4 + (idx & 3)) * BN;
  const int m0 = ((idx >> 2) & 7) * BM;
  const int kz = idx >> 5;
  const int kbase = kz * KC;
  const int lane = t & 63;
  const int wid = t >> 6;
  const int wm = (wid >> 1) * 32;
  const int wn = (wid & 1) * 32;

  f32x4 zero = {0.f, 0.f, 0.f, 0.f};
  f32x4 acc[2][2];
  acc[0][0] = zero; acc[0][1] = zero; acc[1][0] = zero; acc[1][1] = zero;

  // T2 both-sides swizzle: pre-swizzled global source + linear LDS dest +
  // swizzled ds_read. Thread t stages chunk t (row t>>3) and t+256 (row +32).
  const int r0 = t >> 3;
  const int sc = ((t & 7) ^ (r0 & 7)) * 8;
  const unsigned short* gA = A + (size_t)(m0 + r0) * HIDDEN + kbase + sc;
  const unsigned short* gB = Bt + (size_t)(n0 + r0) * HIDDEN + kbase + sc;
  char* lA = (char*)smem + wid * 1024;
  char* lB = (char*)smem + 16384 + wid * 1024;

#define STAGE(buf, kt)                                          \
  do {                                                          \
    const int ko = (kt)*BK;                                     \
    gload_lds16(gA + ko, lA + (buf)*8192);                      \
    gload_lds16(gA + 32 * HIDDEN + ko, lA + (buf)*8192 + 4096); \
    gload_lds16(gB + ko, lB + (buf)*8192);                      \
    gload_lds16(gB + 32 * HIDDEN + ko, lB + (buf)*8192 + 4096); \
  } while (0)

  const int row_a0 = wm + (lane & 15);
  const int row_a1 = row_a0 + 16;
  const int row_b0 = wn + (lane & 15);
  const int row_b1 = row_b0 + 16;
  const int q = lane >> 4;  // 0..3

#define COMPUTE(buf)                                                                    \
  do {                                                                                  \
    _Pragma("unroll") for (int ks = 0; ks < 2; ++ks) {                                  \
      const int cnk = ks * 4 + q;                                                       \
      bf16x8 a0 = *(const bf16x8*)&As[buf][row_a0][(cnk ^ (row_a0 & 7)) * 8];           \
      bf16x8 a1 = *(const bf16x8*)&As[buf][row_a1][(cnk ^ (row_a1 & 7)) * 8];           \
      bf16x8 b0 = *(const bf16x8*)&Bs[buf][row_b0][(cnk ^ (row_b0 & 7)) * 8];           \
      bf16x8 b1 = *(const bf16x8*)&Bs[buf][row_b1][(cnk ^ (row_b1 & 7)) * 8];           \
      acc[0][0] = __builtin_amdgcn_mfma_f32_16x16x32_bf16(a0, b0, acc[0][0], 0, 0, 0);  \
      acc[0][1] = __builtin_amdgcn_mfma_f32_16x16x32_bf16(a0, b1, acc[0][1], 0, 0, 0);  \
      acc[1][0] = __builtin_amdgcn_mfma_f32_16x16x32_bf16(a1, b0, acc[1][0], 0, 0, 0);  \
      acc[1][1] = __builtin_amdgcn_mfma_f32_16x16x32_bf16(a1, b1, acc[1][1], 0, 0, 0);  \
    }                                                                                   \
  } while (0)

  STAGE(0, 0);
  __syncthreads();
  for (int kt = 0; kt < NT; ++kt) {
    const int buf = kt & 1;
    if (kt + 1 < NT) STAGE(buf ^ 1, kt + 1);
    COMPUTE(buf);
    __syncthreads();
  }

  unsigned short* p = part + (size_t)kz * ((size_t)BATCH * HIDDEN);
  const int rb = m0 + wm + (q << 2);
  const int cb = n0 + wn + (lane & 15);
#pragma unroll
  for (int fm = 0; fm < 2; ++fm)
#pragma unroll
    for (int fn = 0; fn < 2; ++fn)
#pragma unroll
      for (int j = 0; j < 4; ++j)
        p[(size_t)(rb + fm * 16 + j) * HIDDEN + cb + fn * 16] = f2bf(acc[fm][fn][j]);
}

// ---- per-layer epilogue: sum bf16 split-K partials, gate, tanh ----
__global__ __launch_bounds__(256) void k_reduce(const unsigned short* __restrict__ part,
                                                const float* __restrict__ prev,
                                                const float* __restrict__ ihl,
                                                const int* __restrict__ token,
                                                float* __restrict__ outf,
                                                unsigned short* __restrict__ outb) {
  const int idx = (blockIdx.x * 256 + threadIdx.x) * 4;
  const int m = idx >> 11;
  const int n = idx & 2047;
  const size_t MN = (size_t)BATCH * HIDDEN;
  float s[4] = {0.f, 0.f, 0.f, 0.f};
#pragma unroll
  for (int kz = 0; kz < SPLITK; ++kz) {
    union { uint2 u; unsigned short h[4]; } v;
    v.u = *(const uint2*)(part + kz * MN + idx);
#pragma unroll
    for (int j = 0; j < 4; ++j) s[j] += bf2f(v.h[j]);
  }
  float4 pv = *(const float4*)(prev + idx);
  const int tok = token[m];
  float4 g = *(const float4*)(ihl + (size_t)tok * HIDDEN + n);
  float4 r;
  r.x = tanh_fast(pv.x + s[0] * g.x);
  r.y = tanh_fast(pv.y + s[1] * g.y);
  r.z = tanh_fast(pv.z + s[2] * g.z);
  r.w = tanh_fast(pv.w + s[3] * g.w);
  *(float4*)(outf + idx) = r;
  if (outb) {
    union { unsigned short h[4]; uint2 u; } o;
    o.h[0] = f2bf(r.x); o.h[1] = f2bf(r.y); o.h[2] = f2bf(r.z); o.h[3] = f2bf(r.w);
    *(uint2*)(outb + idx) = o.u;
  }
}

extern "C" void kernel_launch(void* const* d_in, const int* in_sizes, int n_in,
                              void* d_out, int out_size, void* d_ws, size_t ws_size,
                              hipStream_t stream) {
  const float* state = (const float*)d_in[0];
  const int* token = (const int*)d_in[1];
  const float* ih = (const float*)d_in[2];
  const float* hh = (const float*)d_in[3];
  float* out = (float*)d_out;

  // ws layout (16B-aligned):
  //   Bt   : 6*2048*2048 bf16 = 50331648 B
  //   stb  : 512*2048 bf16    =  2097152 B
  //   sf   : 512*2048 f32     =  4194304 B
  //   part : 4*512*2048 bf16  =  8388608 B
  char* ws = (char*)d_ws;
  unsigned short* bt = (unsigned short*)ws;
  size_t off = (size_t)NLAYERS * HIDDEN * HIDDEN * 2;
  unsigned short* stb = (unsigned short*)(ws + off);
  off += (size_t)BATCH * HIDDEN * 2;
  float* sf = (float*)(ws + off);
  off += (size_t)BATCH * HIDDEN * 4;
  unsigned short* part = (unsigned short*)(ws + off);

  // prep0: transpose layer-0 hh + cvt initial state (everything else hides
  // under the per-layer GEMM launches).
  k_prep0<<<dim3(TRANS_BLOCKS + CVT_BLOCKS), 256, 0, stream>>>(hh, bt, state, stb);

  for (int l = 0; l < NLAYERS; ++l) {
    const bool last = (l == NLAYERS - 1);
    const int nblocks = GEMM_BLOCKS + (last ? 0 : TRANS_BLOCKS);
    k_gemm_trans<<<dim3(nblocks), 256, 0, stream>>>(
        stb, bt + (size_t)l * HIDDEN * HIDDEN, part,
        last ? nullptr : hh + (size_t)(l + 1) * HIDDEN * HIDDEN,
        last ? nullptr : bt + (size_t)(l + 1) * HIDDEN * HIDDEN);
    k_reduce<<<dim3((BATCH * HIDDEN) / 1024), 256, 0, stream>>>(
        part, l == 0 ? state : sf, ih + (size_t)l * VOCAB * HIDDEN, token,
        last ? out : sf, last ? nullptr : stb);
  }
}